// Round 10
// baseline (13550.601 us; speedup 1.0000x reference)
//
#include <hip/hip_runtime.h>
#include <hip/hip_bf16.h>
#include <stdint.h>

typedef unsigned int u32;
typedef unsigned short u16;
typedef short bf16x8 __attribute__((ext_vector_type(8)));
typedef float f32x4 __attribute__((ext_vector_type(4)));
typedef u32 u32x4 __attribute__((ext_vector_type(4)));

#define T_STEPS 1024
#define BATCH   64
#define DIM     1024
#define NWG     64      // one WG per 16 hidden columns
#define NTHR    512     // 8 waves
#define NMAT    3       // z, r, h
#define KSLICE  256     // K per wave (waves 0-3: x-part, 4-7: h-part)
#define DCOLS   16      // hidden columns per WG
#define HROWU   512     // u32 per packed H row (1024 bf16 / 2)

// round-to-nearest-even f32 -> bf16 bits
__device__ __forceinline__ u16 f2bf(float f) {
  u32 u = __float_as_uint(f);
  return (u16)((u + 0x7FFFu + ((u >> 16) & 1u)) >> 16);
}
__device__ __forceinline__ float bflo(u32 w) { return __uint_as_float(w << 16); }
__device__ __forceinline__ float bfhi(u32 w) { return __uint_as_float(w & 0xFFFF0000u); }
__device__ __forceinline__ float sigm(float x) { return 1.0f / (1.0f + __expf(-x)); }
__device__ __forceinline__ float tanh_f(float x) {
  x = fminf(8.0f, fmaxf(-8.0f, x));
  float e = __expf(2.0f * x);
  return (e - 1.0f) / (e + 1.0f);
}

// ---------------- one-time input f32 -> bf16 conversion ----------------
__global__ void gru_xconv(const float* __restrict__ in, u32* __restrict__ xb) {
  size_t i = (size_t)(blockIdx.x * 256 + threadIdx.x) * 8;
  f32x4 lo = *(const f32x4*)(in + i);
  f32x4 hi = *(const f32x4*)(in + i + 4);
  u32x4 o;
  o[0] = ((u32)f2bf(lo[1]) << 16) | f2bf(lo[0]);
  o[1] = ((u32)f2bf(lo[3]) << 16) | f2bf(lo[2]);
  o[2] = ((u32)f2bf(hi[1]) << 16) | f2bf(hi[0]);
  o[3] = ((u32)f2bf(hi[3]) << 16) | f2bf(hi[2]);
  *(u32x4*)(xb + i / 2) = o;
}

// ---------------- pack weights into per-wave register-fragment order (r8-verified) ----------
// k = (wv&3)*256 + ks*32 + (lane>>4)*8 + j   (contiguous-8 kappa; A-loads use the SAME kappa)
// col = wg*16 + (lane&15)
__global__ void gru_pack(const float* __restrict__ Wxz, const float* __restrict__ Whz,
                         const float* __restrict__ Wxr, const float* __restrict__ Whr,
                         const float* __restrict__ Wxh, const float* __restrict__ Whh,
                         u16* __restrict__ wpack) {
  int idx = blockIdx.x * 256 + threadIdx.x;
  if (idx >= NWG * 8 * NMAT * 8 * 64) return;
  int lane = idx & 63; int rest = idx >> 6;
  int ks = rest & 7;  rest >>= 3;
  int n  = rest % NMAT; rest /= NMAT;
  int wv = rest & 7;  int wg = rest >> 3;
  int d  = wg * DCOLS + (lane & 15);
  int k0 = (wv & 3) * KSLICE + ks * 32 + (lane >> 4) * 8;
  const float* W = (wv < 4) ? ((n == 0) ? Wxz : (n == 1) ? Wxr : Wxh)
                            : ((n == 0) ? Whz : (n == 1) ? Whr : Whh);
  u16* dst = wpack + (size_t)idx * 8;
#pragma unroll
  for (int j = 0; j < 8; ++j)
    dst[j] = f2bf(W[(size_t)(k0 + j) * DIM + d]);
}

// ---------------- per-timestep kernel (no cross-WG sync; dispatch boundary = barrier) ----
// Plain cached loads/stores everywhere: the CP's kernel-boundary acquire/release provides
// device-wide visibility of hbuf between dispatches. Races impossible: step t reads
// parity (t-1)&1, writes parity t&1.
__launch_bounds__(NTHR, 2)
__global__ void gru_step(const int t,
                         const u32* __restrict__ xbf,
                         const float* __restrict__ bz, const float* __restrict__ br,
                         const float* __restrict__ bh,
                         const u16* __restrict__ wpack,
                         u32* __restrict__ hbuf, float* __restrict__ out) {
  // partials: 24B cell/lane (4 data words + 2 pad); <=2-way bank aliased (free). 144KB.
  __shared__ float part[8][4][NMAT][64][6];

  const int tid  = threadIdx.x;
  const int wg   = blockIdx.x;
  const int wv   = tid >> 6;
  const int lane = tid & 63;
  const int isH  = (wv >= 4);
  const int arow = lane & 15;
  const int akoff = (lane >> 4) * 8;

  // wave's weight slice: 24 x bf16x8 (96 VGPR)
  bf16x8 breg[NMAT][8];
  {
    const u16* wp = wpack + ((size_t)(wg * 8 + wv) * NMAT * 8 * 64) * 8;
#pragma unroll
    for (int n = 0; n < NMAT; ++n)
#pragma unroll
      for (int ks = 0; ks < 8; ++ks)
        breg[n][ks] = *(const bf16x8*)(wp + ((n * 8 + ks) * 64 + lane) * 8);
  }

  f32x4 acc[4][NMAT];
#pragma unroll
  for (int m = 0; m < 4; ++m)
#pragma unroll
    for (int n = 0; n < NMAT; ++n)
      acc[m][n] = (f32x4){0.f, 0.f, 0.f, 0.f};

  if (!isH) {
    // ---- x-part GEMM: A from bf16 inputs[t] ----
    const u16* xp = (const u16*)xbf + (size_t)t * (BATCH * DIM) + wv * KSLICE + akoff;
#pragma unroll
    for (int m = 0; m < 4; ++m) {
      const u16* rp = xp + (size_t)(m * 16 + arow) * DIM;
#pragma unroll
      for (int ks = 0; ks < 8; ++ks) {
        bf16x8 av = *(const bf16x8*)(rp + ks * 32);
        acc[m][0] = __builtin_amdgcn_mfma_f32_16x16x32_bf16(av, breg[0][ks], acc[m][0], 0, 0, 0);
        acc[m][1] = __builtin_amdgcn_mfma_f32_16x16x32_bf16(av, breg[1][ks], acc[m][1], 0, 0, 0);
        acc[m][2] = __builtin_amdgcn_mfma_f32_16x16x32_bf16(av, breg[2][ks], acc[m][2], 0, 0, 0);
      }
    }
  } else if (t > 0) {
    // ---- h-part GEMM: A from H(t-1) ping-pong buffer, plain cached loads ----
    const u32* hb = hbuf + (size_t)((t - 1) & 1) * (BATCH * HROWU)
                  + (size_t)arow * HROWU + (wv & 3) * 128 + (lane >> 4) * 4;
#pragma unroll
    for (int m = 0; m < 4; ++m) {
      const u32* rm = hb + (size_t)m * 16 * HROWU;
#pragma unroll
      for (int ks = 0; ks < 8; ++ks) {
        u32x4 q = *(const u32x4*)(rm + ks * 16);
        bf16x8 av = __builtin_bit_cast(bf16x8, q);
        acc[m][0] = __builtin_amdgcn_mfma_f32_16x16x32_bf16(av, breg[0][ks], acc[m][0], 0, 0, 0);
        acc[m][1] = __builtin_amdgcn_mfma_f32_16x16x32_bf16(av, breg[1][ks], acc[m][1], 0, 0, 0);
        acc[m][2] = __builtin_amdgcn_mfma_f32_16x16x32_bf16(av, breg[2][ks], acc[m][2], 0, 0, 0);
      }
    }
  }
  // (t==0 h-waves: zero partials, H(-1)=0)

  // ---- publish partials to LDS: lane-cell layout (r8-verified) ----
#pragma unroll
  for (int m = 0; m < 4; ++m)
#pragma unroll
    for (int n = 0; n < NMAT; ++n) {
      *(float2*)&part[wv][m][n][lane][0] = make_float2(acc[m][n][0], acc[m][n][1]);
      *(float2*)&part[wv][m][n][lane][2] = make_float2(acc[m][n][2], acc[m][n][3]);
    }
  __syncthreads();

  // ---- reduce + gates (all 512 threads; 2 outputs each) ----
  const int erow = tid >> 3;
  const int ep   = tid & 7;
  const int dbase = wg * DCOLS;
  const int d0 = dbase + 2 * ep;
  const int em = erow >> 4, er = erow & 15;
  const int cell0 = (er >> 2) * 16 + 2 * ep;
  const int rr_rd = er & 3;

  float zp = bz[d0], zq = bz[d0 + 1];
  float rp = br[d0], rq = br[d0 + 1];
  float xh0 = bh[d0], xh1 = bh[d0 + 1], hh0 = 0.f, hh1 = 0.f;
#pragma unroll
  for (int w = 0; w < 8; ++w) {
    zp += part[w][em][0][cell0][rr_rd];
    zq += part[w][em][0][cell0 + 1][rr_rd];
    rp += part[w][em][1][cell0][rr_rd];
    rq += part[w][em][1][cell0 + 1][rr_rd];
    float h0 = part[w][em][2][cell0][rr_rd];
    float h1 = part[w][em][2][cell0 + 1][rr_rd];
    if (w < 4) { xh0 += h0; xh1 += h1; }   // x-part of candidate (NOT scaled by R)
    else       { hh0 += h0; hh1 += h1; }   // recurrent part (scaled by R)
  }

  // H_prev for this thread's 2 columns (1 packed u32 from the previous-parity buffer)
  float hp0 = 0.f, hp1 = 0.f;
  if (t > 0) {
    u32 hw = hbuf[(size_t)((t - 1) & 1) * (BATCH * HROWU)
                  + (size_t)erow * HROWU + (dbase >> 1) + ep];
    hp0 = bflo(hw); hp1 = bfhi(hw);
  }

  float z0 = sigm(zp), z1 = sigm(zq);
  float r0 = sigm(rp), r1 = sigm(rq);
  float th0 = tanh_f(xh0 + r0 * hh0);
  float th1 = tanh_f(xh1 + r1 * hh1);
  float hn0 = z0 * hp0 + (1.f - z0) * th0;
  float hn1 = z1 * hp1 + (1.f - z1) * th1;

  // publish H(t) (plain store; next dispatch sees it via kernel-boundary coherence)
  {
    u32 pk = ((u32)f2bf(hn1) << 16) | f2bf(hn0);
    hbuf[(size_t)(t & 1) * (BATCH * HROWU) + (size_t)erow * HROWU + (dbase >> 1) + ep] = pk;
  }
  // outputs
  float* op = out + (size_t)t * (BATCH * DIM) + (size_t)erow * DIM + d0;
  *(float2*)op = make_float2(hn0, hn1);
  if (t == T_STEPS - 1) {
    float* fo = out + (size_t)T_STEPS * (BATCH * DIM) + (size_t)erow * DIM + d0;
    *(float2*)fo = make_float2(hn0, hn1);
  }
}

extern "C" void kernel_launch(void* const* d_in, const int* in_sizes, int n_in,
                              void* d_out, int out_size, void* d_ws, size_t ws_size,
                              hipStream_t stream) {
  const float* inputs = (const float*)d_in[0];
  const float* Wxz = (const float*)d_in[1];
  const float* Whz = (const float*)d_in[2];
  const float* bz  = (const float*)d_in[3];
  const float* Wxr = (const float*)d_in[4];
  const float* Whr = (const float*)d_in[5];
  const float* br  = (const float*)d_in[6];
  const float* Wxh = (const float*)d_in[7];
  const float* Whh = (const float*)d_in[8];
  const float* bh  = (const float*)d_in[9];
  float* out = (float*)d_out;

  // ws layout (bytes):
  //   hbuf  @0        (256K: H ping-pong, u32-packed bf16)
  //   wpack @262144   (12.58MB)
  //   xbf   @12845056 (128MB bf16 inputs)
  char* ws = (char*)d_ws;
  u32* hbuf  = (u32*)ws;
  u16* wpack = (u16*)(ws + 262144);
  u32* xbf   = (u32*)(ws + 12845056);
  size_t need = 12845056 + (size_t)T_STEPS * BATCH * DIM * 2;   // ~140.3MB
  if (ws_size < need) return;  // fail visibly (output stays poisoned)

  const int total = NWG * 8 * NMAT * 8 * 64;
  hipLaunchKernelGGL(gru_pack, dim3((total + 255) / 256), dim3(256), 0, stream,
                     Wxz, Whz, Wxr, Whr, Wxh, Whh, wpack);
  hipLaunchKernelGGL(gru_xconv, dim3(T_STEPS * BATCH * DIM / 8 / 256), dim3(256), 0, stream,
                     inputs, xbf);
  // one dispatch per timestep: the kernel boundary IS the global barrier
  for (int t = 0; t < T_STEPS; ++t) {
    hipLaunchKernelGGL(gru_step, dim3(NWG), dim3(NTHR), 0, stream,
                       t, xbf, bz, br, bh, wpack, hbuf, out);
  }
}

// Round 11
// 8478.185 us; speedup vs baseline: 1.5983x; 1.5983x over previous
//
#include <hip/hip_runtime.h>
#include <hip/hip_bf16.h>
#include <stdint.h>

typedef unsigned int u32;
typedef unsigned short u16;
typedef short bf16x8 __attribute__((ext_vector_type(8)));
typedef float f32x4 __attribute__((ext_vector_type(4)));
typedef u32 u32x4 __attribute__((ext_vector_type(4)));

#define T_STEPS 1024
#define BATCH   64
#define DIM     1024
#define NGRP    8        // 8 groups (ideally 1/XCD), 8 batch rows each
#define GWG     32       // WGs per group; each owns 32 hidden cols
#define NTHR    512      // 8 waves

// ctrl u32 indices (64B-strided slots)
#define CTL_XCNT(x)   ((x)*16)
#define CTL_ARR       128
#define CTL_MODE      144
#define CTL_FLAG(g,w) (256 + ((g)*GWG + (w))*16)
#define CTL_U32       4608

__device__ __forceinline__ u16 f2bf(float f) {
  u32 u = __float_as_uint(f);
  return (u16)((u + 0x7FFFu + ((u >> 16) & 1u)) >> 16);
}
__device__ __forceinline__ float bflo(u32 w) { return __uint_as_float(w << 16); }
__device__ __forceinline__ float bfhi(u32 w) { return __uint_as_float(w & 0xFFFF0000u); }
__device__ __forceinline__ float sigm(float x) { return 1.0f / (1.0f + __expf(-x)); }
__device__ __forceinline__ float tanh_f(float x) {
  x = fminf(8.0f, fmaxf(-8.0f, x));
  float e = __expf(2.0f * x);
  return (e - 1.0f) / (e + 1.0f);
}

__global__ void gru_init(u32* ctrl) {
  for (int i = threadIdx.x; i < CTL_U32; i += 512) ctrl[i] = 0;
}

__global__ void gru_xconv(const float* __restrict__ in, u32* __restrict__ xb) {
  size_t i = (size_t)(blockIdx.x * 256 + threadIdx.x) * 8;
  f32x4 lo = *(const f32x4*)(in + i);
  f32x4 hi = *(const f32x4*)(in + i + 4);
  u32x4 o;
  o[0] = ((u32)f2bf(lo[1]) << 16) | f2bf(lo[0]);
  o[1] = ((u32)f2bf(lo[3]) << 16) | f2bf(lo[2]);
  o[2] = ((u32)f2bf(hi[1]) << 16) | f2bf(hi[0]);
  o[3] = ((u32)f2bf(hi[3]) << 16) | f2bf(hi[2]);
  *(u32x4*)(xb + i / 2) = o;
}

// pack (both Wh and Wx): idx = ((((wid*8+wv)*2+cg)*3+n)*4+ks)*64+lane, 8 u16 each
// k0 = wv*128 + ks*32 + (lane>>4)*8 ; col = wid*32 + cg*16 + (lane&15)   (r8-verified recipe)
__global__ void gru_pack3(const float* __restrict__ Wz, const float* __restrict__ Wr,
                          const float* __restrict__ Wh, u16* __restrict__ wp) {
  int idx = blockIdx.x * 256 + threadIdx.x;
  if (idx >= GWG * 8 * 2 * 3 * 4 * 64) return;
  int lane = idx & 63; int r = idx >> 6;
  int ks = r & 3; r >>= 2;
  int n = r % 3; r /= 3;
  int cg = r & 1; r >>= 1;
  int wv = r & 7; int wid = r >> 3;
  int k0 = wv * 128 + ks * 32 + (lane >> 4) * 8;
  int col = wid * 32 + cg * 16 + (lane & 15);
  const float* W = (n == 0) ? Wz : (n == 1) ? Wr : Wh;
  u16* dst = wp + (size_t)idx * 8;
#pragma unroll
  for (int j = 0; j < 8; ++j) dst[j] = f2bf(W[(size_t)(k0 + j) * DIM + col]);
}

#define WAIT0 asm volatile("s_waitcnt vmcnt(0)" ::: "memory"); __builtin_amdgcn_sched_barrier(0)

// MODE 1: H data via XCD L2 (sc0). MODE 2: H data via IC (sc0 sc1). Flags ALWAYS sc0 sc1.
template <int MODE>
__device__ __forceinline__ void scan_run(
    int g, int wid, const u32* __restrict__ xbf,
    const float* __restrict__ bz, const float* __restrict__ br, const float* __restrict__ bh,
    const u16* __restrict__ wpackH, const u16* __restrict__ wpackX,
    u32* hbuf, u32* ctrl, float* __restrict__ out,
    float (&part)[8][2][4][64][6]) {
  const int tid = threadIdx.x;
  const int wv = tid >> 6;
  const int lane = tid & 63;
  u32* hgrp = hbuf + (size_t)g * 8192;          // 2 parity x 4096 u32

  // Wh register-resident: 2cg x 3 x 4ks frags = 96 VGPR
  bf16x8 bregH[2][3][4];
  {
    const u16* wp = wpackH + (size_t)(wid * 8 + wv) * (2 * 3 * 4 * 512);
#pragma unroll
    for (int cg = 0; cg < 2; ++cg)
#pragma unroll
      for (int n = 0; n < 3; ++n)
#pragma unroll
        for (int ks = 0; ks < 4; ++ks) {
          bregH[cg][n][ks] = *(const bf16x8*)(wp + (((cg * 3 + n) * 4 + ks) * 512) + lane * 8);
          asm volatile("" : "+v"(bregH[cg][n][ks]));
        }
  }
  const u16* wxbase = wpackX + (size_t)(wid * 8 + wv) * (2 * 3 * 4 * 512);

  // gate-stage ownership (tid<128): (row, colpair)
  const int grow = tid >> 4;                     // 0..7 (valid when tid<128)
  const int cp = tid & 15;
  const int cgg = cp >> 3;
  const int c16 = 2 * (cp & 7);
  const int col0 = wid * 32 + cgg * 16 + c16;
  const float b_z0 = bz[col0], b_z1 = bz[col0 + 1];
  const float b_r0 = br[col0], b_r1 = br[col0 + 1];
  const float b_h0 = bh[col0], b_h1 = bh[col0 + 1];
  const int cell0 = (grow >> 2) * 16 + c16;
  const int wrd = grow & 3;
  float hp0 = 0.f, hp1 = 0.f;

  f32x4 xc[2][3];
  // ---- x-acc compute for step ts (A rows = this group's 8 batch rows; Wx streamed) ----
#define COMPX(ts) { \
  u32x4 xa0, xa1, xa2, xa3; \
  const u32* xb_ = xbf + (size_t)(ts) * (BATCH * DIM / 2) \
                 + (size_t)(8 * g + (lane & 7)) * (DIM / 2) + wv * 64 + (lane >> 4) * 4; \
  xa0 = *(const u32x4*)(xb_ + 0);  xa1 = *(const u32x4*)(xb_ + 16); \
  xa2 = *(const u32x4*)(xb_ + 32); xa3 = *(const u32x4*)(xb_ + 48); \
  if ((lane & 15) >= 8) { xa0 = (u32x4){0,0,0,0}; xa1 = (u32x4){0,0,0,0}; \
                          xa2 = (u32x4){0,0,0,0}; xa3 = (u32x4){0,0,0,0}; } \
  _Pragma("unroll") for (int cg_ = 0; cg_ < 2; ++cg_) \
  _Pragma("unroll") for (int n_ = 0; n_ < 3; ++n_) { \
    const u16* wq_ = wxbase + ((cg_ * 3 + n_) * 4) * 512 + lane * 8; \
    bf16x8 w0_ = *(const bf16x8*)(wq_);         bf16x8 w1_ = *(const bf16x8*)(wq_ + 512); \
    bf16x8 w2_ = *(const bf16x8*)(wq_ + 1024);  bf16x8 w3_ = *(const bf16x8*)(wq_ + 1536); \
    f32x4 a_ = (f32x4){0.f, 0.f, 0.f, 0.f}; \
    a_ = __builtin_amdgcn_mfma_f32_16x16x32_bf16(__builtin_bit_cast(bf16x8, xa0), w0_, a_, 0, 0, 0); \
    a_ = __builtin_amdgcn_mfma_f32_16x16x32_bf16(__builtin_bit_cast(bf16x8, xa1), w1_, a_, 0, 0, 0); \
    a_ = __builtin_amdgcn_mfma_f32_16x16x32_bf16(__builtin_bit_cast(bf16x8, xa2), w2_, a_, 0, 0, 0); \
    a_ = __builtin_amdgcn_mfma_f32_16x16x32_bf16(__builtin_bit_cast(bf16x8, xa3), w3_, a_, 0, 0, 0); \
    xc[cg_][n_] = a_; } }

  COMPX(0);

#pragma unroll 1
  for (int t = 0; t < T_STEPS; ++t) {
    f32x4 ah[2][3];
#pragma unroll
    for (int cg = 0; cg < 2; ++cg)
#pragma unroll
      for (int n = 0; n < 3; ++n) ah[cg][n] = (f32x4){0.f, 0.f, 0.f, 0.f};

    if (t > 0) {
      // ---- flag poll (ALWAYS IC-coherent; wave wv needs wids 4wv..4wv+3) ----
      const u32* fp = ctrl + CTL_FLAG(g, wv * 4 + (lane & 3));
      for (;;) {
        u32 f;
        asm volatile("global_load_dword %0, %1, off sc0 sc1\n\ts_waitcnt vmcnt(0)"
                     : "=v"(f) : "v"(fp));
        if (__all((lane < 4) ? (int)(f >= (u32)t) : 1)) break;
        __builtin_amdgcn_s_sleep(1);
      }
      asm volatile("" ::: "memory");
      // ---- H(t-1) A-frags (MODE-coherence) + h-MFMA ----
      u32x4 ha0, ha1, ha2, ha3;
      const u32* hb = hgrp + (size_t)((t - 1) & 1) * 4096
                    + (size_t)(lane & 7) * 512 + wv * 64 + (lane >> 4) * 4;
      if (MODE == 1) {
        asm volatile("global_load_dwordx4 %0, %1, off sc0" : "=v"(ha0) : "v"(hb));
        asm volatile("global_load_dwordx4 %0, %1, off offset:64 sc0" : "=v"(ha1) : "v"(hb));
        asm volatile("global_load_dwordx4 %0, %1, off offset:128 sc0" : "=v"(ha2) : "v"(hb));
        asm volatile("global_load_dwordx4 %0, %1, off offset:192 sc0" : "=v"(ha3) : "v"(hb));
      } else {
        asm volatile("global_load_dwordx4 %0, %1, off sc0 sc1" : "=v"(ha0) : "v"(hb));
        asm volatile("global_load_dwordx4 %0, %1, off offset:64 sc0 sc1" : "=v"(ha1) : "v"(hb));
        asm volatile("global_load_dwordx4 %0, %1, off offset:128 sc0 sc1" : "=v"(ha2) : "v"(hb));
        asm volatile("global_load_dwordx4 %0, %1, off offset:192 sc0 sc1" : "=v"(ha3) : "v"(hb));
      }
      WAIT0;
      if ((lane & 15) >= 8) { ha0 = (u32x4){0,0,0,0}; ha1 = (u32x4){0,0,0,0};
                              ha2 = (u32x4){0,0,0,0}; ha3 = (u32x4){0,0,0,0}; }
#pragma unroll
      for (int cg = 0; cg < 2; ++cg)
#pragma unroll
        for (int n = 0; n < 3; ++n) {
          f32x4 a = ah[cg][n];
          a = __builtin_amdgcn_mfma_f32_16x16x32_bf16(__builtin_bit_cast(bf16x8, ha0), bregH[cg][n][0], a, 0, 0, 0);
          a = __builtin_amdgcn_mfma_f32_16x16x32_bf16(__builtin_bit_cast(bf16x8, ha1), bregH[cg][n][1], a, 0, 0, 0);
          a = __builtin_amdgcn_mfma_f32_16x16x32_bf16(__builtin_bit_cast(bf16x8, ha2), bregH[cg][n][2], a, 0, 0, 0);
          a = __builtin_amdgcn_mfma_f32_16x16x32_bf16(__builtin_bit_cast(bf16x8, ha3), bregH[cg][n][3], a, 0, 0, 0);
          ah[cg][n] = a;
        }
    }

    // ---- partials: 4 channels (z=xz+hz, r=xr+hr, xh, hh), lane-cell layout ----
#pragma unroll
    for (int cg = 0; cg < 2; ++cg) {
      f32x4 chz = xc[cg][0] + ah[cg][0];
      f32x4 chr = xc[cg][1] + ah[cg][1];
      f32x4 cxh = xc[cg][2];
      f32x4 chh = ah[cg][2];
      *(float2*)&part[wv][cg][0][lane][0] = make_float2(chz[0], chz[1]);
      *(float2*)&part[wv][cg][0][lane][2] = make_float2(chz[2], chz[3]);
      *(float2*)&part[wv][cg][1][lane][0] = make_float2(chr[0], chr[1]);
      *(float2*)&part[wv][cg][1][lane][2] = make_float2(chr[2], chr[3]);
      *(float2*)&part[wv][cg][2][lane][0] = make_float2(cxh[0], cxh[1]);
      *(float2*)&part[wv][cg][2][lane][2] = make_float2(cxh[2], cxh[3]);
      *(float2*)&part[wv][cg][3][lane][0] = make_float2(chh[0], chh[1]);
      *(float2*)&part[wv][cg][3][lane][2] = make_float2(chh[2], chh[3]);
    }
    __syncthreads();

    float hn0 = 0.f, hn1 = 0.f;
    if (tid < 128) {
      float sz0 = 0, sz1 = 0, sr0 = 0, sr1 = 0, sx0 = 0, sx1 = 0, sh0 = 0, sh1 = 0;
#pragma unroll
      for (int w = 0; w < 8; ++w) {
        sz0 += part[w][cgg][0][cell0][wrd];     sz1 += part[w][cgg][0][cell0 + 1][wrd];
        sr0 += part[w][cgg][1][cell0][wrd];     sr1 += part[w][cgg][1][cell0 + 1][wrd];
        sx0 += part[w][cgg][2][cell0][wrd];     sx1 += part[w][cgg][2][cell0 + 1][wrd];
        sh0 += part[w][cgg][3][cell0][wrd];     sh1 += part[w][cgg][3][cell0 + 1][wrd];
      }
      float z0 = sigm(sz0 + b_z0), z1 = sigm(sz1 + b_z1);
      float r0 = sigm(sr0 + b_r0), r1 = sigm(sr1 + b_r1);
      float th0 = tanh_f(sx0 + b_h0 + r0 * sh0);
      float th1 = tanh_f(sx1 + b_h1 + r1 * sh1);
      hn0 = z0 * hp0 + (1.f - z0) * th0;
      hn1 = z1 * hp1 + (1.f - z1) * th1;
      hp0 = hn0; hp1 = hn1;
      u32 pk = ((u32)f2bf(hn1) << 16) | f2bf(hn0);
      u32* hpw = hgrp + (size_t)(t & 1) * 4096 + (size_t)grow * 512 + wid * 16 + cp;
      if (MODE == 1)
        asm volatile("global_store_dword %0, %1, off sc0" :: "v"(hpw), "v"(pk) : "memory");
      else
        asm volatile("global_store_dword %0, %1, off sc0 sc1" :: "v"(hpw), "v"(pk) : "memory");
    }
    WAIT0;
    __syncthreads();   // all H stores drained before arrival; also LDS WAR
    if (tid == 0) {
      u32* fw = ctrl + CTL_FLAG(g, wid);
      u32 tv = (u32)(t + 1);
      asm volatile("global_store_dword %0, %1, off sc0 sc1" :: "v"(fw), "v"(tv) : "memory");
    }
    // out stores + next x-acc AFTER arrival (overlap partners' polls)
    if (tid < 128) {
      float* op = out + (size_t)t * (BATCH * DIM) + (size_t)(8 * g + grow) * DIM + col0;
      *(float2*)op = make_float2(hn0, hn1);
      if (t == T_STEPS - 1) {
        float* fo = out + (size_t)T_STEPS * (BATCH * DIM) + (size_t)(8 * g + grow) * DIM + col0;
        *(float2*)fo = make_float2(hn0, hn1);
      }
    }
    if (t + 1 < T_STEPS) COMPX(t + 1);
  }
#undef COMPX
}

__launch_bounds__(NTHR, 2)
__global__ void gru_scan(const u32* __restrict__ xbf,
                         const float* __restrict__ bz, const float* __restrict__ br,
                         const float* __restrict__ bh,
                         const u16* __restrict__ wpackH, const u16* __restrict__ wpackX,
                         u32* hbuf, u32* ctrl, float* __restrict__ out) {
  __shared__ float part[8][2][4][64][6];   // 96KB
  __shared__ u32 meta[4];

  // ---- election: pigeonhole-safe, fenced, fallback-capable ----
  if (threadIdx.x == 0) {
    u32 x;
    asm volatile("s_getreg_b32 %0, hwreg(HW_REG_XCC_ID)" : "=s"(x));
    x &= 7;
    u32 tk = __hip_atomic_fetch_add(ctrl + CTL_XCNT(x), 1u,
                                    __ATOMIC_RELAXED, __HIP_MEMORY_SCOPE_AGENT);
    __hip_atomic_fetch_add(ctrl + CTL_ARR, 1u, __ATOMIC_RELEASE, __HIP_MEMORY_SCOPE_AGENT);
    while (__hip_atomic_load(ctrl + CTL_ARR, __ATOMIC_ACQUIRE, __HIP_MEMORY_SCOPE_AGENT)
           < (u32)(NGRP * GWG))
      __builtin_amdgcn_s_sleep(4);
    if (blockIdx.x == 0) {
      u32 uni = 1;
      for (int i = 0; i < 8; ++i)
        if (__hip_atomic_load(ctrl + CTL_XCNT(i), __ATOMIC_RELAXED,
                              __HIP_MEMORY_SCOPE_AGENT) != GWG) uni = 0;
      __hip_atomic_store(ctrl + CTL_MODE, uni ? 1u : 2u,
                         __ATOMIC_RELEASE, __HIP_MEMORY_SCOPE_AGENT);
    }
    u32 m;
    for (;;) {
      m = __hip_atomic_load(ctrl + CTL_MODE, __ATOMIC_ACQUIRE, __HIP_MEMORY_SCOPE_AGENT);
      if (m != 0) break;
      __builtin_amdgcn_s_sleep(4);
    }
    meta[0] = m;
    meta[1] = (m == 1) ? x : (blockIdx.x >> 5);
    meta[2] = (m == 1) ? tk : (blockIdx.x & 31);
  }
  __syncthreads();
  const u32 m = meta[0];
  const int g = (int)meta[1];
  const int wid = (int)meta[2];
  if (m == 1 && wid >= GWG) return;   // paranoia: can't occur when uniform

  if (m == 1) scan_run<1>(g, wid, xbf, bz, br, bh, wpackH, wpackX, hbuf, ctrl, out, part);
  else        scan_run<2>(g, wid, xbf, bz, br, bh, wpackH, wpackX, hbuf, ctrl, out, part);
}

extern "C" void kernel_launch(void* const* d_in, const int* in_sizes, int n_in,
                              void* d_out, int out_size, void* d_ws, size_t ws_size,
                              hipStream_t stream) {
  const float* inputs = (const float*)d_in[0];
  const float* Wxz = (const float*)d_in[1];
  const float* Whz = (const float*)d_in[2];
  const float* bz  = (const float*)d_in[3];
  const float* Wxr = (const float*)d_in[4];
  const float* Whr = (const float*)d_in[5];
  const float* br  = (const float*)d_in[6];
  const float* Wxh = (const float*)d_in[7];
  const float* Whh = (const float*)d_in[8];
  const float* bh  = (const float*)d_in[9];
  float* out = (float*)d_out;

  // ws: ctrl@0 (32K) | hbuf@32K (256K: 8 groups x 2 parity x 16KB) | wpackH@288K (6.29MB)
  //     | wpackX (6.29MB) | xbf (128MB)  => ~147MB total
  char* ws = (char*)d_ws;
  u32* ctrl   = (u32*)ws;
  u32* hbuf   = (u32*)(ws + 32768);
  u16* wpackH = (u16*)(ws + 294912);
  u16* wpackX = (u16*)(ws + 294912 + 6291456);
  u32* xbf    = (u32*)(ws + 294912 + 2 * 6291456);
  size_t need = 294912 + 2 * 6291456 + (size_t)T_STEPS * BATCH * DIM * 2;
  if (ws_size < need) return;  // fail visibly

  const int pk = GWG * 8 * 2 * 3 * 4 * 64;
  hipLaunchKernelGGL(gru_init, dim3(1), dim3(512), 0, stream, ctrl);
  hipLaunchKernelGGL(gru_pack3, dim3((pk + 255) / 256), dim3(256), 0, stream,
                     Whz, Whr, Whh, wpackH);
  hipLaunchKernelGGL(gru_pack3, dim3((pk + 255) / 256), dim3(256), 0, stream,
                     Wxz, Wxr, Wxh, wpackX);
  hipLaunchKernelGGL(gru_xconv, dim3(T_STEPS * BATCH * DIM / 8 / 256), dim3(256), 0, stream,
                     inputs, xbf);
  hipLaunchKernelGGL(gru_scan, dim3(NGRP * GWG), dim3(NTHR), 0, stream,
                     xbf, bz, br, bh, wpackH, wpackX, hbuf, ctrl, out);
}

// Round 13
// 6666.622 us; speedup vs baseline: 2.0326x; 1.2717x over previous
//
#include <hip/hip_runtime.h>
#include <hip/hip_bf16.h>
#include <stdint.h>

typedef unsigned int u32;
typedef unsigned short u16;
typedef short bf16x8 __attribute__((ext_vector_type(8)));
typedef float f32x4 __attribute__((ext_vector_type(4)));
typedef u32 u32x4 __attribute__((ext_vector_type(4)));

#define T_STEPS 1024
#define BATCH   64
#define DIM     1024
#define NGRP    8        // 8 groups (one per XCD in mode 1), 8 batch rows each
#define GWG     32       // WGs per group; each owns 32 hidden cols
#define NTHR    512      // 8 waves

// ctrl u32 indices (64B-strided slots)
#define CTL_XCNT(x)   ((x)*16)
#define CTL_ARR       128
#define CTL_MODE      144
#define CTL_FLAG(g,w) (256 + ((g)*GWG + (w))*16)
#define CTL_U32       4608

__device__ __forceinline__ u16 f2bf(float f) {
  u32 u = __float_as_uint(f);
  return (u16)((u + 0x7FFFu + ((u >> 16) & 1u)) >> 16);
}
__device__ __forceinline__ float sigm(float x) { return 1.0f / (1.0f + __expf(-x)); }
__device__ __forceinline__ float tanh_f(float x) {
  x = fminf(8.0f, fmaxf(-8.0f, x));
  float e = __expf(2.0f * x);
  return (e - 1.0f) / (e + 1.0f);
}

__global__ void gru_init(u32* ctrl) {
  for (int i = threadIdx.x; i < CTL_U32; i += 512) ctrl[i] = 0;
}

__global__ void gru_xconv(const float* __restrict__ in, u32* __restrict__ xb) {
  size_t i = (size_t)(blockIdx.x * 256 + threadIdx.x) * 8;
  f32x4 lo = *(const f32x4*)(in + i);
  f32x4 hi = *(const f32x4*)(in + i + 4);
  u32x4 o;
  o[0] = ((u32)f2bf(lo[1]) << 16) | f2bf(lo[0]);
  o[1] = ((u32)f2bf(lo[3]) << 16) | f2bf(lo[2]);
  o[2] = ((u32)f2bf(hi[1]) << 16) | f2bf(hi[0]);
  o[3] = ((u32)f2bf(hi[3]) << 16) | f2bf(hi[2]);
  *(u32x4*)(xb + i / 2) = o;
}

// pack: idx = ((((wid*8+wv)*2+cg)*3+n)*4+ks)*64+lane, 8 u16 each (r8/r11-verified)
// k0 = wv*128 + ks*32 + (lane>>4)*8 ; col = wid*32 + cg*16 + (lane&15)
__global__ void gru_pack3(const float* __restrict__ Wz, const float* __restrict__ Wr,
                          const float* __restrict__ Wh, u16* __restrict__ wp) {
  int idx = blockIdx.x * 256 + threadIdx.x;
  if (idx >= GWG * 8 * 2 * 3 * 4 * 64) return;
  int lane = idx & 63; int r = idx >> 6;
  int ks = r & 3; r >>= 2;
  int n = r % 3; r /= 3;
  int cg = r & 1; r >>= 1;
  int wv = r & 7; int wid = r >> 3;
  int k0 = wv * 128 + ks * 32 + (lane >> 4) * 8;
  int col = wid * 32 + cg * 16 + (lane & 15);
  const float* W = (n == 0) ? Wz : (n == 1) ? Wr : Wh;
  u16* dst = wp + (size_t)idx * 8;
#pragma unroll
  for (int j = 0; j < 8; ++j) dst[j] = f2bf(W[(size_t)(k0 + j) * DIM + col]);
}

#define WAIT0 asm volatile("s_waitcnt vmcnt(0)" ::: "memory"); __builtin_amdgcn_sched_barrier(0)
#define MFMA_(A, B, C) __builtin_amdgcn_mfma_f32_16x16x32_bf16(__builtin_bit_cast(bf16x8, A), B, C, 0, 0, 0)

// MODE 1: H data via XCD L2 (sc0). MODE 2: H data via IC (sc0 sc1).
// Flags ALWAYS sc0 sc1 (IC) in BOTH modes — r11's hang-proofing, restored.
template <int MODE>
__device__ __forceinline__ void scan_run(
    int g, int wid, const u32* __restrict__ xbf,
    const float* __restrict__ bz, const float* __restrict__ br, const float* __restrict__ bh,
    const u16* __restrict__ wpackH, const u16* __restrict__ wpackX,
    u32* hbuf, u32* ctrl, float* __restrict__ out,
    float (&part)[8][2][4][64][6]) {
  const int tid = threadIdx.x;
  const int wv = tid >> 6;
  const int lane = tid & 63;
  u32* hgrp = hbuf + (size_t)g * 8192;          // 2 parity x 4096 u32

  // Wh + Wx register-resident: 2 x 96 VGPR (asm-laundered against remat)
  bf16x8 bregH[2][3][4], bregX[2][3][4];
  {
    const u16* wph = wpackH + (size_t)(wid * 8 + wv) * (2 * 3 * 4 * 512);
    const u16* wpx = wpackX + (size_t)(wid * 8 + wv) * (2 * 3 * 4 * 512);
#pragma unroll
    for (int cg = 0; cg < 2; ++cg)
#pragma unroll
      for (int n = 0; n < 3; ++n)
#pragma unroll
        for (int ks = 0; ks < 4; ++ks) {
          const int off = (((cg * 3 + n) * 4 + ks) * 512) + lane * 8;
          bregH[cg][n][ks] = *(const bf16x8*)(wph + off);
          asm volatile("" : "+v"(bregH[cg][n][ks]));
          bregX[cg][n][ks] = *(const bf16x8*)(wpx + off);
          asm volatile("" : "+v"(bregX[cg][n][ks]));
        }
  }

  // gate-stage ownership (tid<128): (row, colpair)
  const int grow = tid >> 4;                     // 0..7 (valid when tid<128)
  const int cp = tid & 15;
  const int cgg = cp >> 3;
  const int c16 = 2 * (cp & 7);
  const int col0 = wid * 32 + cgg * 16 + c16;
  const float b_z0 = bz[col0], b_z1 = bz[col0 + 1];
  const float b_r0 = br[col0], b_r1 = br[col0 + 1];
  const float b_h0 = bh[col0], b_h1 = bh[col0 + 1];
  const int cell0 = (grow >> 2) * 16 + c16;
  const int wrd = grow & 3;
  float hp0 = 0.f, hp1 = 0.f;

  f32x4 xc[2][3];
  // x-acc for step ts: A = this group's 8 batch rows (rows 8-15 zeroed), Wx from REGISTERS
#define COMPX(ts) { \
  u32x4 xa0, xa1, xa2, xa3; \
  const u32* xb_ = xbf + (size_t)(ts) * (BATCH * DIM / 2) \
                 + (size_t)(8 * g + (lane & 7)) * (DIM / 2) + wv * 64 + (lane >> 4) * 4; \
  xa0 = *(const u32x4*)(xb_ + 0);  xa1 = *(const u32x4*)(xb_ + 16); \
  xa2 = *(const u32x4*)(xb_ + 32); xa3 = *(const u32x4*)(xb_ + 48); \
  if ((lane & 15) >= 8) { xa0 = (u32x4){0,0,0,0}; xa1 = (u32x4){0,0,0,0}; \
                          xa2 = (u32x4){0,0,0,0}; xa3 = (u32x4){0,0,0,0}; } \
  _Pragma("unroll") for (int cg_ = 0; cg_ < 2; ++cg_) \
  _Pragma("unroll") for (int n_ = 0; n_ < 3; ++n_) { \
    f32x4 a_ = (f32x4){0.f, 0.f, 0.f, 0.f}; \
    a_ = MFMA_(xa0, bregX[cg_][n_][0], a_); \
    a_ = MFMA_(xa1, bregX[cg_][n_][1], a_); \
    a_ = MFMA_(xa2, bregX[cg_][n_][2], a_); \
    a_ = MFMA_(xa3, bregX[cg_][n_][3], a_); \
    xc[cg_][n_] = a_; } }

  COMPX(0);

#pragma unroll 1
  for (int t = 0; t < T_STEPS; ++t) {
    // z/r channels: h-MFMA accumulates DIRECTLY into the x-partial (C-in = xc)
    f32x4 vz[2], vr[2], vhh[2];
#pragma unroll
    for (int cg = 0; cg < 2; ++cg) {
      vz[cg] = xc[cg][0]; vr[cg] = xc[cg][1]; vhh[cg] = (f32x4){0.f, 0.f, 0.f, 0.f};
    }

    if (t > 0) {
      // ---- flag poll: ALWAYS IC-coherent (sc0 sc1); wave wv needs wids 4wv..4wv+3 ----
      const u32* fp = ctrl + CTL_FLAG(g, wv * 4 + (lane & 3));
      for (;;) {
        u32 f;
        asm volatile("global_load_dword %0, %1, off sc0 sc1\n\ts_waitcnt vmcnt(0)"
                     : "=v"(f) : "v"(fp));
        if (__all((lane < 4) ? (int)(f >= (u32)t) : 1)) break;
        __builtin_amdgcn_s_sleep(1);
      }
      asm volatile("" ::: "memory");
      // ---- H(t-1) A-frags (MODE-coherence, r11-proven) ----
      u32x4 ha0, ha1, ha2, ha3;
      const u32* hb = hgrp + (size_t)((t - 1) & 1) * 4096
                    + (size_t)(lane & 7) * 512 + wv * 64 + (lane >> 4) * 4;
      if (MODE == 1) {
        asm volatile("global_load_dwordx4 %0, %1, off sc0" : "=v"(ha0) : "v"(hb));
        asm volatile("global_load_dwordx4 %0, %1, off offset:64 sc0" : "=v"(ha1) : "v"(hb));
        asm volatile("global_load_dwordx4 %0, %1, off offset:128 sc0" : "=v"(ha2) : "v"(hb));
        asm volatile("global_load_dwordx4 %0, %1, off offset:192 sc0" : "=v"(ha3) : "v"(hb));
      } else {
        asm volatile("global_load_dwordx4 %0, %1, off sc0 sc1" : "=v"(ha0) : "v"(hb));
        asm volatile("global_load_dwordx4 %0, %1, off offset:64 sc0 sc1" : "=v"(ha1) : "v"(hb));
        asm volatile("global_load_dwordx4 %0, %1, off offset:128 sc0 sc1" : "=v"(ha2) : "v"(hb));
        asm volatile("global_load_dwordx4 %0, %1, off offset:192 sc0 sc1" : "=v"(ha3) : "v"(hb));
      }
      WAIT0;
      if ((lane & 15) >= 8) { ha0 = (u32x4){0,0,0,0}; ha1 = (u32x4){0,0,0,0};
                              ha2 = (u32x4){0,0,0,0}; ha3 = (u32x4){0,0,0,0}; }
#pragma unroll
      for (int cg = 0; cg < 2; ++cg) {
        vz[cg] = MFMA_(ha0, bregH[cg][0][0], vz[cg]);
        vz[cg] = MFMA_(ha1, bregH[cg][0][1], vz[cg]);
        vz[cg] = MFMA_(ha2, bregH[cg][0][2], vz[cg]);
        vz[cg] = MFMA_(ha3, bregH[cg][0][3], vz[cg]);
        vr[cg] = MFMA_(ha0, bregH[cg][1][0], vr[cg]);
        vr[cg] = MFMA_(ha1, bregH[cg][1][1], vr[cg]);
        vr[cg] = MFMA_(ha2, bregH[cg][1][2], vr[cg]);
        vr[cg] = MFMA_(ha3, bregH[cg][1][3], vr[cg]);
        vhh[cg] = MFMA_(ha0, bregH[cg][2][0], vhh[cg]);
        vhh[cg] = MFMA_(ha1, bregH[cg][2][1], vhh[cg]);
        vhh[cg] = MFMA_(ha2, bregH[cg][2][2], vhh[cg]);
        vhh[cg] = MFMA_(ha3, bregH[cg][2][3], vhh[cg]);
      }
    }

    // ---- partials: z (x+h), r (x+h), xh, hh — lane-cell layout ----
#pragma unroll
    for (int cg = 0; cg < 2; ++cg) {
      *(float2*)&part[wv][cg][0][lane][0] = make_float2(vz[cg][0], vz[cg][1]);
      *(float2*)&part[wv][cg][0][lane][2] = make_float2(vz[cg][2], vz[cg][3]);
      *(float2*)&part[wv][cg][1][lane][0] = make_float2(vr[cg][0], vr[cg][1]);
      *(float2*)&part[wv][cg][1][lane][2] = make_float2(vr[cg][2], vr[cg][3]);
      *(float2*)&part[wv][cg][2][lane][0] = make_float2(xc[cg][2][0], xc[cg][2][1]);
      *(float2*)&part[wv][cg][2][lane][2] = make_float2(xc[cg][2][2], xc[cg][2][3]);
      *(float2*)&part[wv][cg][3][lane][0] = make_float2(vhh[cg][0], vhh[cg][1]);
      *(float2*)&part[wv][cg][3][lane][2] = make_float2(vhh[cg][2], vhh[cg][3]);
    }
    __syncthreads();

    float hn0 = 0.f, hn1 = 0.f;
    if (tid < 128) {
      float sz0 = 0, sz1 = 0, sr0 = 0, sr1 = 0, sx0 = 0, sx1 = 0, sh0 = 0, sh1 = 0;
#pragma unroll
      for (int w = 0; w < 8; ++w) {
        sz0 += part[w][cgg][0][cell0][wrd];     sz1 += part[w][cgg][0][cell0 + 1][wrd];
        sr0 += part[w][cgg][1][cell0][wrd];     sr1 += part[w][cgg][1][cell0 + 1][wrd];
        sx0 += part[w][cgg][2][cell0][wrd];     sx1 += part[w][cgg][2][cell0 + 1][wrd];
        sh0 += part[w][cgg][3][cell0][wrd];     sh1 += part[w][cgg][3][cell0 + 1][wrd];
      }
      float z0 = sigm(sz0 + b_z0), z1 = sigm(sz1 + b_z1);
      float r0 = sigm(sr0 + b_r0), r1 = sigm(sr1 + b_r1);
      float th0 = tanh_f(sx0 + b_h0 + r0 * sh0);
      float th1 = tanh_f(sx1 + b_h1 + r1 * sh1);
      hn0 = z0 * hp0 + (1.f - z0) * th0;
      hn1 = z1 * hp1 + (1.f - z1) * th1;
      hp0 = hn0; hp1 = hn1;
      u32 pk = ((u32)f2bf(hn1) << 16) | f2bf(hn0);
      u32* hpw = hgrp + (size_t)(t & 1) * 4096 + (size_t)grow * 512 + wid * 16 + cp;
      if (MODE == 1)
        asm volatile("global_store_dword %0, %1, off sc0" :: "v"(hpw), "v"(pk) : "memory");
      else
        asm volatile("global_store_dword %0, %1, off sc0 sc1" :: "v"(hpw), "v"(pk) : "memory");
    }
    WAIT0;
    __syncthreads();   // all H stores drained before arrival; also LDS WAR
    if (tid == 0) {
      u32* fw = ctrl + CTL_FLAG(g, wid);
      u32 tv = (u32)(t + 1);
      asm volatile("global_store_dword %0, %1, off sc0 sc1" :: "v"(fw), "v"(tv) : "memory");
    }
    // out stores + next x-acc AFTER arrival (overlap partners' polls)
    if (tid < 128) {
      float* op = out + (size_t)t * (BATCH * DIM) + (size_t)(8 * g + grow) * DIM + col0;
      *(float2*)op = make_float2(hn0, hn1);
      if (t == T_STEPS - 1) {
        float* fo = out + (size_t)T_STEPS * (BATCH * DIM) + (size_t)(8 * g + grow) * DIM + col0;
        *(float2*)fo = make_float2(hn0, hn1);
      }
    }
    if (t + 1 < T_STEPS) COMPX(t + 1);
  }
#undef COMPX
}

__launch_bounds__(NTHR, 2)
__global__ void gru_scan(const u32* __restrict__ xbf,
                         const float* __restrict__ bz, const float* __restrict__ br,
                         const float* __restrict__ bh,
                         const u16* __restrict__ wpackH, const u16* __restrict__ wpackX,
                         u32* hbuf, u32* ctrl, float* __restrict__ out) {
  __shared__ float part[8][2][4][64][6];   // 96KB
  __shared__ u32 meta[4];

  // ---- election: pigeonhole-safe, fenced, fallback-capable (r11-verified) ----
  if (threadIdx.x == 0) {
    u32 x;
    asm volatile("s_getreg_b32 %0, hwreg(HW_REG_XCC_ID)" : "=s"(x));
    x &= 7;
    u32 tk = __hip_atomic_fetch_add(ctrl + CTL_XCNT(x), 1u,
                                    __ATOMIC_RELAXED, __HIP_MEMORY_SCOPE_AGENT);
    __hip_atomic_fetch_add(ctrl + CTL_ARR, 1u, __ATOMIC_RELEASE, __HIP_MEMORY_SCOPE_AGENT);
    while (__hip_atomic_load(ctrl + CTL_ARR, __ATOMIC_ACQUIRE, __HIP_MEMORY_SCOPE_AGENT)
           < (u32)(NGRP * GWG))
      __builtin_amdgcn_s_sleep(4);
    if (blockIdx.x == 0) {
      u32 uni = 1;
      for (int i = 0; i < 8; ++i)
        if (__hip_atomic_load(ctrl + CTL_XCNT(i), __ATOMIC_RELAXED,
                              __HIP_MEMORY_SCOPE_AGENT) != GWG) uni = 0;
      __hip_atomic_store(ctrl + CTL_MODE, uni ? 1u : 2u,
                         __ATOMIC_RELEASE, __HIP_MEMORY_SCOPE_AGENT);
    }
    u32 m;
    for (;;) {
      m = __hip_atomic_load(ctrl + CTL_MODE, __ATOMIC_ACQUIRE, __HIP_MEMORY_SCOPE_AGENT);
      if (m != 0) break;
      __builtin_amdgcn_s_sleep(4);
    }
    meta[0] = m;
    meta[1] = (m == 1) ? x : (blockIdx.x >> 5);
    meta[2] = (m == 1) ? tk : (blockIdx.x & 31);
  }
  __syncthreads();
  const u32 m = meta[0];
  const int g = (int)meta[1];
  const int wid = (int)meta[2];
  if (m == 1 && wid >= GWG) return;   // paranoia: can't occur when uniform

  if (m == 1) scan_run<1>(g, wid, xbf, bz, br, bh, wpackH, wpackX, hbuf, ctrl, out, part);
  else        scan_run<2>(g, wid, xbf, bz, br, bh, wpackH, wpackX, hbuf, ctrl, out, part);
}

extern "C" void kernel_launch(void* const* d_in, const int* in_sizes, int n_in,
                              void* d_out, int out_size, void* d_ws, size_t ws_size,
                              hipStream_t stream) {
  const float* inputs = (const float*)d_in[0];
  const float* Wxz = (const float*)d_in[1];
  const float* Whz = (const float*)d_in[2];
  const float* bz  = (const float*)d_in[3];
  const float* Wxr = (const float*)d_in[4];
  const float* Whr = (const float*)d_in[5];
  const float* br  = (const float*)d_in[6];
  const float* Wxh = (const float*)d_in[7];
  const float* Whh = (const float*)d_in[8];
  const float* bh  = (const float*)d_in[9];
  float* out = (float*)d_out;

  // ws: ctrl@0 (32K) | hbuf@32K (256K) | wpackH@288K (6.29MB) | wpackX (6.29MB) | xbf (128MB)
  char* ws = (char*)d_ws;
  u32* ctrl   = (u32*)ws;
  u32* hbuf   = (u32*)(ws + 32768);
  u16* wpackH = (u16*)(ws + 294912);
  u16* wpackX = (u16*)(ws + 294912 + 6291456);
  u32* xbf    = (u32*)(ws + 294912 + 2 * 6291456);
  size_t need = 294912 + 2 * 6291456 + (size_t)T_STEPS * BATCH * DIM * 2;
  if (ws_size < need) return;  // fail visibly

  const int pk = GWG * 8 * 2 * 3 * 4 * 64;
  hipLaunchKernelGGL(gru_init, dim3(1), dim3(512), 0, stream, ctrl);
  hipLaunchKernelGGL(gru_pack3, dim3((pk + 255) / 256), dim3(256), 0, stream,
                     Whz, Whr, Whh, wpackH);
  hipLaunchKernelGGL(gru_pack3, dim3((pk + 255) / 256), dim3(256), 0, stream,
                     Wxz, Wxr, Wxh, wpackX);
  hipLaunchKernelGGL(gru_xconv, dim3(T_STEPS * BATCH * DIM / 8 / 256), dim3(256), 0, stream,
                     inputs, xbf);
  hipLaunchKernelGGL(gru_scan, dim3(NGRP * GWG), dim3(NTHR), 0, stream,
                     xbf, bz, br, bh, wpackH, wpackX, hbuf, ctrl, out);
}